// Round 7
// baseline (248.086 us; speedup 1.0000x reference)
//
#include <hip/hip_runtime.h>
#include <string.h>

// Integer-quantized MHA. Phase 1: exact-int i8 MFMA with Karatsuba digit GEMM.
// Phase 2: native bf16 MFMA (r_q<=255 and vt mantissa are 8-significand-bit ->
// exact products in bf16/fp32; only >2^24 accumulation rounds, +-few ulp).
// B=2,H=16 (BH=32), T=S=1024, HC=128, G=8. Output int32.

typedef int   v4i __attribute__((ext_vector_type(4)));
typedef float v4f __attribute__((ext_vector_type(4)));
typedef short v8s __attribute__((ext_vector_type(8)));

#define BHN 32
#define TN  1024
#define SN  1024
#define HCN 128
#define TT  16
#define RST 1032               // rbuf row stride (u16): 2064 B == 4 dwords mod 32 banks
#define KD_BH 393216           // 8 chunks * 48 KB (3 planes)
#define VD_BH 262144           // 32 kb * 8 n * 64 lanes * 16 B (bf16 frags)
#define WS_NEED ((size_t)BHN*(KD_BH+VD_BH))   // 20 MB

__device__ __forceinline__ unsigned pack_b(int b0,int b1,int b2,int b3){
    return (unsigned)((b0&255)|((b1&255)<<8)|((b2&255)<<16)|((b3&255)<<24));
}

// digitize 16 consecutive dequantized ints into hi/lo/sum i8 digit vectors
__device__ __forceinline__ void dig16s(const int* __restrict__ p, int s0, int s1,
                                       v4i& hi, v4i& lo, v4i& sm){
    #pragma unroll
    for (int wi=0; wi<4; ++wi){
        v4i m = *(const v4i*)(p + wi*4);
        int s = (wi<2) ? s0 : s1;
        int d0=m[0]<<s, d1=m[1]<<s, d2=m[2]<<s, d3=m[3]<<s;
        int h0=d0>>4, h1=d1>>4, h2=d2>>4, h3=d3>>4;
        int l0=d0&15, l1=d1&15, l2=d2&15, l3=d3&15;
        hi[wi] = (int)pack_b(h0,h1,h2,h3);
        lo[wi] = (int)pack_b(l0,l1,l2,l3);
        sm[wi] = (int)pack_b(h0+l0,h1+l1,h2+l2,h3+l3);
    }
}

__device__ __forceinline__ unsigned short bf16_of_int(int v){
    return (unsigned short)(__float_as_uint((float)v) >> 16);   // exact: <=8 sig bits
}

// ---------------- pre-pass ----------------
// kd: per bh, 8 chunks of 48KB = [n(8)][kc(2)][plane(3:hi,lo,sum)][lane64][16B]
// vd: per bh, bf16 frags = [kb(32)][n(8)][lane64][16B]  (8 bf16 per lane)
__global__ __launch_bounds__(256) void digitize(
    const int* __restrict__ k_q, const int* __restrict__ k_s,
    const int* __restrict__ vt_q, const int* __restrict__ vt_s,
    unsigned char* __restrict__ kd, unsigned char* __restrict__ vd)
{
    const int g = blockIdx.x*256 + threadIdx.x;
    const int ioff = g*16;
    if (blockIdx.y == 0){
        int row = ioff>>7, c0 = ioff&127;              // row over 32*1024 s-rows
        int s0 = k_s[(row<<4)+(c0>>3)], s1 = k_s[(row<<4)+(c0>>3)+1];
        v4i hi, lo, sm;
        dig16s(k_q + ioff, s0, s1, hi, lo, sm);
        int bh = row>>10, srow = row&1023;
        int ch = srow>>7, lr = srow&127, n = lr>>4, l15 = lr&15;
        int kc = c0>>6, q4 = (c0>>4)&3;
        size_t base = (size_t)bh*KD_BH + (size_t)ch*49152u
                    + (size_t)(((n*2+kc)*3)*1024 + (q4*16+l15)*16);
        *(v4i*)(kd + base)        = hi;
        *(v4i*)(kd + base + 1024) = lo;
        *(v4i*)(kd + base + 2048) = sm;
    } else {
        int grow = ioff>>10, s4 = ioff&1023;           // grow = bh*128+chan
        int sc0 = vt_s[(grow<<7)+(s4>>3)], sc1 = vt_s[(grow<<7)+(s4>>3)+1];
        int bh = grow>>7, chan = grow&127;
        int n = chan>>4, l15 = chan&15;
        int kb = s4>>5, q0 = (s4>>3)&3;                // s4 16-aligned -> q0 in {0,2}
        const int* vp = vt_q + ioff;
        #pragma unroll
        for (int h=0; h<2; ++h){                       // two quads of 8
            int s = (h==0) ? sc0 : sc1;
            unsigned wds[4];
            #pragma unroll
            for (int j=0; j<4; ++j){
                int a = vp[h*8 + j*2]   << s;
                int b = vp[h*8 + j*2+1] << s;
                wds[j] = (unsigned)bf16_of_int(a) | ((unsigned)bf16_of_int(b) << 16);
            }
            size_t base = (size_t)bh*VD_BH
                        + (size_t)(((kb*8 + n)*64 + (q0+h)*16 + l15)*16);
            *(v4i*)(vd + base) = v4i{(int)wds[0],(int)wds[1],(int)wds[2],(int)wds[3]};
        }
    }
}

// ---------------- main fused kernel ----------------
template<bool PK>
__global__ __launch_bounds__(256,4) void mha_mfma(
    const int* __restrict__ q_q, const int* __restrict__ q_s,
    const int* __restrict__ k_q, const int* __restrict__ k_s,
    const int* __restrict__ vt_q, const int* __restrict__ vt_s,
    const unsigned char* __restrict__ kd, const unsigned char* __restrict__ vd,
    int* __restrict__ out)
{
    __shared__ unsigned short rbuf[16*RST];      // 33 KB r values as bf16, granule swizzle
    __shared__ float red[128];                   // cross-wave softmax reductions

    const int tid  = threadIdx.x;
    const int ln   = tid & 15;
    const int qd4  = (tid >> 4) & 3;
    const int w    = tid >> 6;
    const int lane = tid & 63;
    // XCD-aware swizzle: each XCD's share covers only 4 bh -> digit images fit its L2.
    const int blk = blockIdx.x;
    const int bh  = ((blk>>9)<<3) | (blk&7);
    const int t0  = ((blk>>3)&63) * TT;

    // ---- Q A-fragments in registers (hi/lo/sum digits) ----
    v4i qfh[2], qfl[2], qfs[2];
    {
        const int* qrow  = q_q + (size_t)(bh*TN + t0 + ln)*HCN;
        const int* qsrow = q_s + (size_t)(bh*TN + t0 + ln)*16;
        #pragma unroll
        for (int kc=0; kc<2; ++kc){
            int gi = kc*8 + qd4*2;
            dig16s(qrow + kc*64 + qd4*16, qsrow[gi], qsrow[gi+1],
                   qfh[kc], qfl[kc], qfs[kc]);
        }
    }

    int scv[16][4];   // scores / exp bits, MFMA C-layout: row=qd4*4+r, col=tile*16+ln

    // ================= phase 1: QK scores (exact int, Karatsuba) =================
    const v4i* kb_ = (const v4i*)(kd + (size_t)bh*KD_BH);
    #pragma unroll 2
    for (int ch=0; ch<8; ++ch){
        #pragma unroll
        for (int i=0;i<2;i++){
            const int n = w*2 + i;
            v4i ahh{0,0,0,0}, ap3{0,0,0,0}, all{0,0,0,0};
            #pragma unroll
            for (int kc=0;kc<2;kc++){
                v4i kh, kl, ks;
                if (PK){
                    const v4i* tb = kb_ + ch*3072 + (n*2+kc)*192 + lane;
                    kh = tb[0]; kl = tb[64]; ks = tb[128];
                } else {
                    int srow = bh*SN + ch*128 + n*16 + ln;
                    int cc   = kc*64 + qd4*16;
                    dig16s(k_q + (size_t)srow*128 + cc,
                           k_s[srow*16 + (cc>>3)], k_s[srow*16 + (cc>>3) + 1],
                           kh, kl, ks);
                }
                ahh = __builtin_amdgcn_mfma_i32_16x16x64_i8(qfh[kc], kh, ahh, 0,0,0);
                ap3 = __builtin_amdgcn_mfma_i32_16x16x64_i8(qfs[kc], ks, ap3, 0,0,0);
                all = __builtin_amdgcn_mfma_i32_16x16x64_i8(qfl[kc], kl, all, 0,0,0);
            }
            int st = ch*2 + i;
            #pragma unroll
            for (int r=0;r<4;r++){
                int mid = ap3[r] - ahh[r] - all[r];          // HL+LH
                scv[st][r] = (ahh[r]<<8) + (mid<<4) + all[r];
            }
        }
    }

    // ================= softmax + group-of-8 po2 requant =================
    const float CS = (float)(6.103515625e-05 / 11.313708498984760390566); // f32(2^-14/sqrt(128))
    float mx[4], sm[4];
    #pragma unroll
    for (int r=0;r<4;r++){
        float m_ = -3.0e38f;
        #pragma unroll
        for (int st=0;st<16;st++) m_ = fmaxf(m_, (float)scv[st][r]*CS);
        #pragma unroll
        for (int o=8;o>0;o>>=1) m_ = fmaxf(m_, __shfl_xor(m_, o));
        mx[r] = m_;
    }
    if (ln == 0){
        #pragma unroll
        for (int r=0;r<4;r++) red[w*16 + qd4*4 + r] = mx[r];
    }
    __syncthreads();
    #pragma unroll
    for (int r=0;r<4;r++){
        float m_ = fmaxf(fmaxf(red[qd4*4+r], red[16+qd4*4+r]),
                         fmaxf(red[32+qd4*4+r], red[48+qd4*4+r]));
        float s_ = 0.f;
        #pragma unroll
        for (int st=0;st<16;st++){
            float e = expf((float)scv[st][r]*CS - m_);
            scv[st][r] = __float_as_int(e);
            s_ += e;
        }
        #pragma unroll
        for (int o=8;o>0;o>>=1) s_ += __shfl_xor(s_, o);
        sm[r] = s_;
    }
    if (ln == 0){
        #pragma unroll
        for (int r=0;r<4;r++) red[64 + w*16 + qd4*4 + r] = sm[r];
    }
    __syncthreads();
    float inv14[4];
    #pragma unroll
    for (int r=0;r<4;r++){
        float s_ = red[64+qd4*4+r] + red[80+qd4*4+r] + red[96+qd4*4+r] + red[112+qd4*4+r];
        inv14[r] = 16384.0f / s_;      // one IEEE div per row
    }

    #pragma unroll
    for (int st=0;st<16;st++){
        int colb = (st>>1)*128 + (w*2+(st&1))*16;
        #pragma unroll
        for (int r=0;r<4;r++){
            float val = rintf(__int_as_float(scv[st][r]) * inv14[r]);
            float g = val;
            g = fmaxf(g, __shfl_xor(g, 1));
            g = fmaxf(g, __shfl_xor(g, 2));
            g = fmaxf(g, __shfl_xor(g, 4));
            int gi = max((int)g, 1);
            int x = gi - 1;
            int e = 31 - __clz(x | 255);
            int sh = (e - 7) + ((x >> (e - 7)) == 255);   // == clip(ceil(log2(gi/255)),0,)
            float rq = fminf(rintf(val * __int_as_float((127-sh)<<23)), 255.0f);
            int rv = ((int)rq) << sh;                     // r <= 16384, 8 sig bits
            int row = qd4*4 + r;
            int col = colb + ln;
            int gs  = (col>>3) ^ (row&7);
            rbuf[row*RST + gs*8 + (col&7)] = bf16_of_int(rv);
        }
    }
    __syncthreads();

    // ================= phase 2: out = r @ vt^T (bf16 MFMA) =================
    const v4i* vb = (const v4i*)(vd + (size_t)bh*VD_BH);
    v4f acc0{0,0,0,0}, acc1{0,0,0,0};
    #pragma unroll 4
    for (int kb=0; kb<32; ++kb){
        // A frag: r[t=ln][s = kb*32 + qd4*8 + j], 8 bf16 = one b128 from LDS
        v8s af = *(const v8s*)(rbuf + ln*RST + (((kb*4+qd4) ^ (ln&7))<<3));
        v4i b0, b1;
        if (PK){
            b0 = vb[(kb*8 + w*2    )*64 + lane];
            b1 = vb[(kb*8 + w*2 + 1)*64 + lane];
        } else {
            #pragma unroll
            for (int i=0;i<2;i++){
                int chan = (w*2+i)*16 + ln;
                const int* vp = vt_q + (size_t)(bh*HCN + chan)*SN + kb*32 + qd4*8;
                int s = vt_s[(bh*HCN + chan)*128 + kb*4 + qd4];
                unsigned wd[4];
                #pragma unroll
                for (int j=0;j<4;j++){
                    int a = vp[j*2]   << s;
                    int b = vp[j*2+1] << s;
                    wd[j] = (unsigned)bf16_of_int(a) | ((unsigned)bf16_of_int(b)<<16);
                }
                v4i t{(int)wd[0],(int)wd[1],(int)wd[2],(int)wd[3]};
                if (i==0) b0 = t; else b1 = t;
            }
        }
        v8s bs0, bs1;
        memcpy(&bs0, &b0, 16);
        memcpy(&bs1, &b1, 16);
        acc0 = __builtin_amdgcn_mfma_f32_16x16x32_bf16(af, bs0, acc0, 0,0,0);
        acc1 = __builtin_amdgcn_mfma_f32_16x16x32_bf16(af, bs1, acc1, 0,0,0);
    }
    #pragma unroll
    for (int r=0;r<4;r++){
        size_t o = (size_t)(bh*TN + t0 + qd4*4 + r)*HCN + (w*2)*16 + ln;
        out[o]      = (int)rintf(acc0[r]);
        out[o + 16] = (int)rintf(acc1[r]);
    }
}

extern "C" void kernel_launch(void* const* d_in, const int* in_sizes, int n_in,
                              void* d_out, int out_size, void* d_ws, size_t ws_size,
                              hipStream_t stream) {
    const int* q_q  = (const int*)d_in[0];
    const int* q_s  = (const int*)d_in[1];
    const int* k_q  = (const int*)d_in[2];
    const int* k_s  = (const int*)d_in[3];
    const int* vt_q = (const int*)d_in[4];
    const int* vt_s = (const int*)d_in[5];
    int* out = (int*)d_out;

    unsigned char* kd = (unsigned char*)d_ws;
    unsigned char* vd = kd + (size_t)BHN*KD_BH;

    if (ws_size >= WS_NEED){
        digitize<<<dim3(1024,2), 256, 0, stream>>>(k_q,k_s,vt_q,vt_s, kd,vd);
        mha_mfma<true><<<dim3(2048), 256, 0, stream>>>(
            q_q,q_s,k_q,k_s,vt_q,vt_s, kd,vd, out);
    } else {
        mha_mfma<false><<<dim3(2048), 256, 0, stream>>>(
            q_q,q_s,k_q,k_s,vt_q,vt_s, kd,vd, out);
    }
}

// Round 8
// 172.406 us; speedup vs baseline: 1.4390x; 1.4390x over previous
//
#include <hip/hip_runtime.h>
#include <string.h>

// Integer-quantized MHA. Phase 1: exact-int i8 K=64 MFMA digit GEMM (R6 form —
// register-neutral, fits 128-reg budget at 4 waves/SIMD; Karatsuba reverted, it
// caused scratch spills). Phase 2: native bf16 MFMA (r_q<=255, vt mantissa 8-bit
// -> exact products; only >2^24 accumulation rounds).
// B=2,H=16 (BH=32), T=S=1024, HC=128, G=8. Output int32.

typedef int   v4i __attribute__((ext_vector_type(4)));
typedef float v4f __attribute__((ext_vector_type(4)));
typedef short v8s __attribute__((ext_vector_type(8)));

#define BHN 32
#define TN  1024
#define SN  1024
#define HCN 128
#define TT  16
#define RST 1032               // rbuf row stride (u16): 2064 B == 16 mod 128 -> conflict-free
#define KD_BH 262144           // 8 chunks * 32 KB (2 planes, fragment-ordered)
#define VD_BH 262144           // 32 kb * 8 n * 64 lanes * 16 B (bf16 frags)
#define WS_NEED ((size_t)BHN*(KD_BH+VD_BH))   // 16 MB

__device__ __forceinline__ unsigned pack_b(int b0,int b1,int b2,int b3){
    return (unsigned)((b0&255)|((b1&255)<<8)|((b2&255)<<16)|((b3&255)<<24));
}

// digitize 16 consecutive dequantized ints (2 scale groups) into hi/lo i8 digit vectors
__device__ __forceinline__ void dig16(const int* __restrict__ p, int s0, int s1,
                                      v4i& hi, v4i& lo){
    #pragma unroll
    for (int wi=0; wi<4; ++wi){
        v4i m = *(const v4i*)(p + wi*4);
        int s = (wi<2) ? s0 : s1;
        int d0=m[0]<<s, d1=m[1]<<s, d2=m[2]<<s, d3=m[3]<<s;
        hi[wi] = (int)pack_b(d0>>4,d1>>4,d2>>4,d3>>4);
        lo[wi] = (int)pack_b(d0&15,d1&15,d2&15,d3&15);
    }
}

__device__ __forceinline__ unsigned short bf16_of_int(int v){
    return (unsigned short)(__float_as_uint((float)v) >> 16);   // exact: <=8 sig bits
}

// ---------------- pre-pass ----------------
// kd: per bh, 8 chunks of 32KB = [n(8)][kc(2)][plane(2:hi,lo)][lane64][16B]
// vd: per bh, bf16 frags = [kb(32)][n(8)][lane64][16B]  (8 bf16 per lane)
__global__ __launch_bounds__(256) void digitize(
    const int* __restrict__ k_q, const int* __restrict__ k_s,
    const int* __restrict__ vt_q, const int* __restrict__ vt_s,
    unsigned char* __restrict__ kd, unsigned char* __restrict__ vd)
{
    const int g = blockIdx.x*256 + threadIdx.x;
    const int ioff = g*16;
    if (blockIdx.y == 0){
        int row = ioff>>7, c0 = ioff&127;              // row over 32*1024 s-rows
        int s0 = k_s[(row<<4)+(c0>>3)], s1 = k_s[(row<<4)+(c0>>3)+1];
        v4i hi, lo;
        dig16(k_q + ioff, s0, s1, hi, lo);
        int bh = row>>10, srow = row&1023;
        int ch = srow>>7, lr = srow&127, n = lr>>4, l15 = lr&15;
        int kc = c0>>6, q4 = (c0>>4)&3;
        size_t base = (size_t)bh*KD_BH + (size_t)ch*32768u
                    + (size_t)(n*4096 + kc*2048 + (q4*16+l15)*16);
        *(v4i*)(kd + base)        = hi;
        *(v4i*)(kd + base + 1024) = lo;
    } else {
        int grow = ioff>>10, s4 = ioff&1023;           // grow = bh*128+chan
        int sc0 = vt_s[(grow<<7)+(s4>>3)], sc1 = vt_s[(grow<<7)+(s4>>3)+1];
        int bh = grow>>7, chan = grow&127;
        int n = chan>>4, l15 = chan&15;
        int kb = s4>>5, q0 = (s4>>3)&3;                // s4 16-aligned -> q0 in {0,2}
        const int* vp = vt_q + ioff;
        #pragma unroll
        for (int h=0; h<2; ++h){                       // two quads of 8
            int s = (h==0) ? sc0 : sc1;
            unsigned wds[4];
            #pragma unroll
            for (int j=0; j<4; ++j){
                int a = vp[h*8 + j*2]   << s;
                int b = vp[h*8 + j*2+1] << s;
                wds[j] = (unsigned)bf16_of_int(a) | ((unsigned)bf16_of_int(b) << 16);
            }
            size_t base = (size_t)bh*VD_BH
                        + (size_t)(((kb*8 + n)*64 + (q0+h)*16 + l15)*16);
            *(v4i*)(vd + base) = v4i{(int)wds[0],(int)wds[1],(int)wds[2],(int)wds[3]};
        }
    }
}

// ---------------- main fused kernel ----------------
template<bool PK>
__global__ __launch_bounds__(256,4) void mha_mfma(
    const int* __restrict__ q_q, const int* __restrict__ q_s,
    const int* __restrict__ k_q, const int* __restrict__ k_s,
    const int* __restrict__ vt_q, const int* __restrict__ vt_s,
    const unsigned char* __restrict__ kd, const unsigned char* __restrict__ vd,
    int* __restrict__ out)
{
    __shared__ unsigned short rbuf[16*RST];      // 33 KB r values as bf16, granule swizzle
    __shared__ float red[128];                   // cross-wave softmax reductions

    const int tid  = threadIdx.x;
    const int ln   = tid & 15;
    const int qd4  = (tid >> 4) & 3;
    const int w    = tid >> 6;
    const int lane = tid & 63;
    // XCD-aware swizzle: each XCD's share covers only 4 bh -> digit images fit its L2.
    const int blk = blockIdx.x;
    const int bh  = ((blk>>9)<<3) | (blk&7);
    const int t0  = ((blk>>3)&63) * TT;

    // ---- Q A-fragments in registers (digitized in-reg from global) ----
    v4i qfh[2], qfl[2];
    {
        const int* qrow  = q_q + (size_t)(bh*TN + t0 + ln)*HCN;
        const int* qsrow = q_s + (size_t)(bh*TN + t0 + ln)*16;
        #pragma unroll
        for (int kc=0; kc<2; ++kc){
            int gi = kc*8 + qd4*2;
            dig16(qrow + kc*64 + qd4*16, qsrow[gi], qsrow[gi+1], qfh[kc], qfl[kc]);
        }
    }

    int scv[16][4];   // scores / exp bits, MFMA C-layout: row=qd4*4+r, col=tile*16+ln

    // ================= phase 1: QK scores (barrier-free, exact int) =================
    const v4i* kb_ = (const v4i*)(kd + (size_t)bh*KD_BH);
    for (int ch=0; ch<8; ++ch){
        #pragma unroll
        for (int i=0;i<2;i++){
            const int n = w*2 + i;
            v4i a2{0,0,0,0}, a1{0,0,0,0}, a0{0,0,0,0};
            #pragma unroll
            for (int kc=0;kc<2;kc++){
                v4i bhv, blv;
                if (PK){
                    const v4i* tb = kb_ + (ch*8+n)*256 + kc*128 + lane;
                    bhv = tb[0];
                    blv = tb[64];
                } else {
                    int srow = bh*SN + ch*128 + n*16 + ln;
                    int cc   = kc*64 + qd4*16;
                    dig16(k_q + (size_t)srow*128 + cc,
                          k_s[srow*16 + (cc>>3)], k_s[srow*16 + (cc>>3) + 1], bhv, blv);
                }
                a2 = __builtin_amdgcn_mfma_i32_16x16x64_i8(qfh[kc], bhv, a2, 0,0,0);
                a1 = __builtin_amdgcn_mfma_i32_16x16x64_i8(qfl[kc], bhv, a1, 0,0,0);
                a1 = __builtin_amdgcn_mfma_i32_16x16x64_i8(qfh[kc], blv, a1, 0,0,0);
                a0 = __builtin_amdgcn_mfma_i32_16x16x64_i8(qfl[kc], blv, a0, 0,0,0);
            }
            int st = ch*2 + i;
            #pragma unroll
            for (int r=0;r<4;r++)
                scv[st][r] = (a2[r]<<8) + (a1[r]<<4) + a0[r];
        }
    }

    // ================= softmax + group-of-8 po2 requant =================
    const float CS = (float)(6.103515625e-05 / 11.313708498984760390566); // f32(2^-14/sqrt(128))
    float mx[4], sm[4];
    #pragma unroll
    for (int r=0;r<4;r++){
        float m_ = -3.0e38f;
        #pragma unroll
        for (int st=0;st<16;st++) m_ = fmaxf(m_, (float)scv[st][r]*CS);
        #pragma unroll
        for (int o=8;o>0;o>>=1) m_ = fmaxf(m_, __shfl_xor(m_, o));
        mx[r] = m_;
    }
    if (ln == 0){
        #pragma unroll
        for (int r=0;r<4;r++) red[w*16 + qd4*4 + r] = mx[r];
    }
    __syncthreads();
    #pragma unroll
    for (int r=0;r<4;r++){
        float m_ = fmaxf(fmaxf(red[qd4*4+r], red[16+qd4*4+r]),
                         fmaxf(red[32+qd4*4+r], red[48+qd4*4+r]));
        float s_ = 0.f;
        #pragma unroll
        for (int st=0;st<16;st++){
            float e = expf((float)scv[st][r]*CS - m_);
            scv[st][r] = __float_as_int(e);
            s_ += e;
        }
        #pragma unroll
        for (int o=8;o>0;o>>=1) s_ += __shfl_xor(s_, o);
        sm[r] = s_;
    }
    if (ln == 0){
        #pragma unroll
        for (int r=0;r<4;r++) red[64 + w*16 + qd4*4 + r] = sm[r];
    }
    __syncthreads();
    float inv14[4];
    #pragma unroll
    for (int r=0;r<4;r++){
        float s_ = red[64+qd4*4+r] + red[80+qd4*4+r] + red[96+qd4*4+r] + red[112+qd4*4+r];
        inv14[r] = 16384.0f / s_;      // one IEEE div per row
    }

    #pragma unroll
    for (int st=0;st<16;st++){
        int colb = (st>>1)*128 + (w*2+(st&1))*16;
        #pragma unroll
        for (int r=0;r<4;r++){
            float val = rintf(__int_as_float(scv[st][r]) * inv14[r]);
            float g = val;
            g = fmaxf(g, __shfl_xor(g, 1));
            g = fmaxf(g, __shfl_xor(g, 2));
            g = fmaxf(g, __shfl_xor(g, 4));
            int gi = max((int)g, 1);
            int x = gi - 1;
            int e = 31 - __clz(x | 255);
            int sh = (e - 7) + ((x >> (e - 7)) == 255);   // == clip(ceil(log2(gi/255)),0,)
            float rq = fminf(rintf(val * __int_as_float((127-sh)<<23)), 255.0f);
            int rv = ((int)rq) << sh;                     // r <= 16384, 8 sig bits
            int row = qd4*4 + r;
            int col = colb + ln;
            int gs  = (col>>3) ^ (row&7);
            rbuf[row*RST + gs*8 + (col&7)] = bf16_of_int(rv);
        }
    }
    __syncthreads();

    // ================= phase 2: out = r @ vt^T (bf16 MFMA, barrier-free) =================
    const v4i* vb = (const v4i*)(vd + (size_t)bh*VD_BH);
    v4f acc0{0,0,0,0}, acc1{0,0,0,0};
    #pragma unroll 4
    for (int kb=0; kb<32; ++kb){
        // A frag: r[t=ln][s = kb*32 + qd4*8 + j], 8 bf16 = one b128 from LDS
        v8s af = *(const v8s*)(rbuf + ln*RST + (((kb*4+qd4) ^ (ln&7))<<3));
        v4i b0, b1;
        if (PK){
            b0 = vb[(kb*8 + w*2    )*64 + lane];
            b1 = vb[(kb*8 + w*2 + 1)*64 + lane];
        } else {
            #pragma unroll
            for (int i=0;i<2;i++){
                int chan = (w*2+i)*16 + ln;
                const int* vp = vt_q + (size_t)(bh*HCN + chan)*SN + kb*32 + qd4*8;
                int s = vt_s[(bh*HCN + chan)*128 + kb*4 + qd4];
                unsigned wd[4];
                #pragma unroll
                for (int j=0;j<4;j++){
                    int a = vp[j*2]   << s;
                    int b = vp[j*2+1] << s;
                    wd[j] = (unsigned)bf16_of_int(a) | ((unsigned)bf16_of_int(b)<<16);
                }
                v4i t{(int)wd[0],(int)wd[1],(int)wd[2],(int)wd[3]};
                if (i==0) b0 = t; else b1 = t;
            }
        }
        v8s bs0, bs1;
        memcpy(&bs0, &b0, 16);
        memcpy(&bs1, &b1, 16);
        acc0 = __builtin_amdgcn_mfma_f32_16x16x32_bf16(af, bs0, acc0, 0,0,0);
        acc1 = __builtin_amdgcn_mfma_f32_16x16x32_bf16(af, bs1, acc1, 0,0,0);
    }
    #pragma unroll
    for (int r=0;r<4;r++){
        size_t o = (size_t)(bh*TN + t0 + qd4*4 + r)*HCN + (w*2)*16 + ln;
        out[o]      = (int)rintf(acc0[r]);
        out[o + 16] = (int)rintf(acc1[r]);
    }
}

extern "C" void kernel_launch(void* const* d_in, const int* in_sizes, int n_in,
                              void* d_out, int out_size, void* d_ws, size_t ws_size,
                              hipStream_t stream) {
    const int* q_q  = (const int*)d_in[0];
    const int* q_s  = (const int*)d_in[1];
    const int* k_q  = (const int*)d_in[2];
    const int* k_s  = (const int*)d_in[3];
    const int* vt_q = (const int*)d_in[4];
    const int* vt_s = (const int*)d_in[5];
    int* out = (int*)d_out;

    unsigned char* kd = (unsigned char*)d_ws;
    unsigned char* vd = kd + (size_t)BHN*KD_BH;

    if (ws_size >= WS_NEED){
        digitize<<<dim3(1024,2), 256, 0, stream>>>(k_q,k_s,vt_q,vt_s, kd,vd);
        mha_mfma<true><<<dim3(2048), 256, 0, stream>>>(
            q_q,q_s,k_q,k_s,vt_q,vt_s, kd,vd, out);
    } else {
        mha_mfma<false><<<dim3(2048), 256, 0, stream>>>(
            q_q,q_s,k_q,k_s,vt_q,vt_s, kd,vd, out);
    }
}